// Round 7
// baseline (143.271 us; speedup 1.0000x reference)
//
#include <hip/hip_runtime.h>
#include <hip/hip_fp16.h>
#include <math.h>

// CTC loss forward, two kernels, LINEAR-domain recurrence (beta transform).
//   beta[s,t] = alpha[s,t] - cum_blank(t):  blank transitions have weight 1:
//     nO = (aO + pE + skip*pO) * w,  w = e^{x_lab - x_blank}   (label states)
//     nE = aE + aO                                             (blank states)
//   Per-step chain: 2 DPP wave_shr:1 + fma + add + mul, no transcendentals.
// Round-6 lesson (absmax hit 48 = threshold): renorm max over ALL states
// flushes the readout cone for short labels (junk states s>2LL exceed it by
// ~137 bits). FIX: w=0 for lanes >= label_length -> junk states are exactly 0,
// renorm max = max over readout cone. Round-6 lesson 2: fused single block
// serializes phase1 (26us) and phase2 (29us). FIX: split kernels; prep writes
// w fp16 to GLOBAL in chunk layout [b][chunk][lane][8] so the chain kernel
// does ONE coalesced dwordx4 per lane per 8 steps, prefetched 8 chunks ahead.
// B=256, T=512, C=128 (blank=127), L=64, S=129.

constexpr int Cc = 128;
constexpr int Tt = 512;
constexpr int Ll = 64;
constexpr int NC = Tt / 8;            // 64 chunks of 8 timesteps
constexpr float INV_LN2 = 1.4426950408889634f;
constexpr float LN2_F   = 0.6931471805599453f;

__device__ __forceinline__ float fexp2(float x) { return __builtin_amdgcn_exp2f(x); }
__device__ __forceinline__ float flog2(float x) { return __builtin_amdgcn_logf(x); }

template<int CTRL, bool BC>
__device__ __forceinline__ float dppf(float old, float x) {
    return __int_as_float(__builtin_amdgcn_update_dpp(
        __float_as_int(old), __float_as_int(x), CTRL, 0xF, 0xF, BC));
}
// lane i <- lane i-1 across whole wave; lane 0 <- fill. (silicon-proven r3-r6)
__device__ __forceinline__ float wshr1(float x, float fill) { return dppf<0x138, false>(fill, x); }

__device__ __forceinline__ float rlf(float v, int lane) {
    return __int_as_float(__builtin_amdgcn_readlane(__float_as_int(v), lane));
}
// Row-local (16-lane) reduce; lanes 15/31/47/63 hold row results. (proven r6)
__device__ __forceinline__ float rowsum(float e) {
    e += dppf<0x111, true>(0.f, e);
    e += dppf<0x112, true>(0.f, e);
    e += dppf<0x114, true>(0.f, e);
    e += dppf<0x118, true>(0.f, e);
    return e;
}
__device__ __forceinline__ float rowmax(float m) {   // m >= 0 (0-fill identity)
    m = fmaxf(m, dppf<0x111, true>(0.f, m));
    m = fmaxf(m, dppf<0x112, true>(0.f, m));
    m = fmaxf(m, dppf<0x114, true>(0.f, m));
    m = fmaxf(m, dppf<0x118, true>(0.f, m));
    return m;
}
__device__ __forceinline__ float allsum(float e) {
    e = rowsum(e);
    return (rlf(e, 15) + rlf(e, 31)) + (rlf(e, 47) + rlf(e, 63));
}
__device__ __forceinline__ float allmax(float m) {
    m = rowmax(m);
    return fmaxf(fmaxf(rlf(m, 15), rlf(m, 31)), fmaxf(rlf(m, 47), rlf(m, 63)));
}
__device__ __forceinline__ float bperm_f(int srclane, float v) {
    return __int_as_float(__builtin_amdgcn_ds_bpermute(srclane << 2, __float_as_int(v)));
}
__device__ __forceinline__ float gather4(float4 v, int srclane, int csel) {
    const float gx = bperm_f(srclane, v.x), gy = bperm_f(srclane, v.y);
    const float gz = bperm_f(srclane, v.z), gw = bperm_f(srclane, v.w);
    const float lo = (csel & 1) ? gy : gx;
    const float hi = (csel & 1) ? gw : gz;
    return (csel & 2) ? hi : lo;
}

// ---------------- Kernel 1: prep (streaming, fully parallel) ----------------
// One block (4 waves) per batch b. Wave w handles rows [w*128, w*128+128).
// Outputs: lpb[b][t] fp32 (log2 p_blank), w_ws[b][chunk][lane][8] fp16.
__global__ __launch_bounds__(256, 1) void ctc_prep_kernel(
    const int* __restrict__ y_true, const float* __restrict__ y_pred,
    const int* __restrict__ lab_len,
    float* __restrict__ lpb_ws, __half* __restrict__ w_ws)
{
    const int b   = blockIdx.x;
    const int tid = threadIdx.x;
    const int w   = tid >> 6;
    const int l   = tid & 63;

    int LLv = lab_len[b]; if (LLv < 1) LLv = 1; if (LLv > Ll) LLv = Ll;
    const int lab = y_true[b * Ll + l] & 127;
    const float* rowbase = y_pred + (size_t)b * Tt * Cc;
    float* lpb = lpb_ws + b * Tt;
    __half* wbase = w_ws + ((size_t)b * NC) * 64 * 8;

    const int half = l >> 5, li = l & 31;
    const int srcA = lab >> 2;
    const int csel = lab & 3;
    const int tbase = w * 128;
    const bool live = (l < LLv);         // round-6 fix: junk lanes -> w = 0

    float4 vb[4];
#pragma unroll
    for (int j = 0; j < 4; ++j)
        vb[j] = ((const float4*)(rowbase + (size_t)(tbase + 2 * j + half) * Cc))[li];

    for (int i = 0; i < 64; i += 4) {
        unsigned pw[4];
#pragma unroll
        for (int j = 0; j < 4; ++j) {
            const float4 v = vb[j];
            const int nx = i + 4 + j;
            if (nx < 64)
                vb[j] = ((const float4*)(rowbase + (size_t)(tbase + 2 * nx + half) * Cc))[li];

            const int rA = tbase + 2 * (i + j);
            const int rB = rA + 1;

            float e = (fexp2(v.x * INV_LN2) + fexp2(v.y * INV_LN2))
                    + (fexp2(v.z * INV_LN2) + fexp2(v.w * INV_LN2));
            e = rowsum(e);
            const float sA = rlf(e, 15) + rlf(e, 31);
            const float sB = rlf(e, 47) + rlf(e, 63);
            const float lsA = flog2(sA), lsB = flog2(sB);
            const float blA = rlf(v.w, 31);
            const float blB = rlf(v.w, 63);

            if (l == 0)
                ((float2*)(lpb + rA))[0] =
                    make_float2(fmaf(blA, INV_LN2, -lsA), fmaf(blB, INV_LN2, -lsB));

            const float xA = gather4(v, srcA, csel);
            const float xB = gather4(v, srcA + 32, csel);
            float wA = fminf(fmaxf(fexp2((xA - blA) * INV_LN2), 6.1e-5f), 8192.0f);
            float wB = fminf(fmaxf(fexp2((xB - blB) * INV_LN2), 6.1e-5f), 8192.0f);
            wA = live ? wA : 0.0f;
            wB = live ? wB : 0.0f;
            pw[j] = (unsigned)__half_as_ushort(__float2half(wA))
                  | ((unsigned)__half_as_ushort(__float2half(wB)) << 16);
        }
        const int chunk = (tbase + 2 * i) >> 3;
        ((uint4*)(wbase + ((size_t)chunk * 64 + l) * 8))[0] =
            make_uint4(pw[0], pw[1], pw[2], pw[3]);
    }
}

// ---------------- Kernel 2: chain (one wave per batch) ----------------
template<bool GUARD>
__device__ __forceinline__ void do_chunk(uint4 raw, int t0, int inlen, float skf,
                                         float& aO, float& aE, float& r0, float& Rtot)
{
    float dv[8];
    {
        const __half2 h0 = *reinterpret_cast<const __half2*>(&raw.x);
        const __half2 h1 = *reinterpret_cast<const __half2*>(&raw.y);
        const __half2 h2 = *reinterpret_cast<const __half2*>(&raw.z);
        const __half2 h3 = *reinterpret_cast<const __half2*>(&raw.w);
        dv[0] = __low2float(h0); dv[1] = __high2float(h0);
        dv[2] = __low2float(h1); dv[3] = __high2float(h1);
        dv[4] = __low2float(h2); dv[5] = __high2float(h2);
        dv[6] = __low2float(h3); dv[7] = __high2float(h3);
    }
#pragma unroll
    for (int j = 0; j < 8; ++j) {
        if (!GUARD || (t0 + j < inlen)) {
            const float pE = wshr1(aE, r0);     // beta[2l]; lane0: state0
            const float pO = wshr1(aO, 0.0f);   // beta[2l-1]
            const float nO = (fmaf(skf, pO, pE) + aO) * dv[j];
            aE += aO;
            aO = nO;
        }
    }
    // zero-lag renorm (proven r6); max >= 1 once any aE absorbed mass -> R >= 0
    const float M_ = allmax(fmaxf(fmaxf(aO, aE), r0));
    int R_ = (int)(__float_as_uint(M_) >> 23) - 127;
    R_ = (R_ < 0) ? 0 : ((R_ > 126) ? 126 : R_);
    const float sc = __uint_as_float((unsigned)(127 - R_) << 23);
    aO = fminf(aO * sc, 4.0f);
    aE = fminf(aE * sc, 4.0f);
    r0 = fminf(r0 * sc, 4.0f);
    Rtot += (float)R_;
}

__global__ __launch_bounds__(64, 1) void ctc_chain_kernel(
    const int* __restrict__ y_true, const int* __restrict__ in_len,
    const int* __restrict__ lab_len,
    const float* __restrict__ lpb_ws, const __half* __restrict__ w_ws,
    float* __restrict__ out)
{
    const int b = blockIdx.x;
    const int l = threadIdx.x;

    int inlen = in_len[b]; if (inlen < 1) inlen = 1; if (inlen > Tt) inlen = Tt;
    int LLv   = lab_len[b]; if (LLv < 1) LLv = 1; if (LLv > Ll) LLv = Ll;

    const int lab  = y_true[b * Ll + l] & 127;
    const int labp = __shfl_up(lab, 1, 64);
    const float skf = ((l >= 1) && (lab != labp)) ? 1.0f : 0.0f;

    const float* lpb = lpb_ws + b * Tt;
    const uint4* wp  = (const uint4*)w_ws + (size_t)b * NC * 64;

    // cum_blank inputs: issue early, reduce at end
    float cb8[8];
#pragma unroll
    for (int j = 0; j < 8; ++j) cb8[j] = lpb[j * 64 + l];

#define LOADGRP(G, BUF) { _Pragma("unroll")                               \
        for (int c = 0; c < 8; ++c) BUF[c] = wp[(size_t)(((G) * 8 + c) * 64 + l)]; }

    float aO = 0.0f, aE = 0.0f, r0 = 1.0f, Rtot = 0.0f;

    uint4 A[8], Bv[8];
    LOADGRP(0, A);

    for (int g = 0; ; ) {
        const int base = g * 64;
        const bool full = (base + 64 <= inlen);
        const bool last = (base + 64 >= inlen);
        if (!last) LOADGRP(g + 1, Bv);       // 8 dwordx4 in flight over 64 steps
        if (full) {
#pragma unroll
            for (int c = 0; c < 8; ++c)
                do_chunk<false>(A[c], base + 8 * c, inlen, skf, aO, aE, r0, Rtot);
        } else {
#pragma unroll
            for (int c = 0; c < 8; ++c) {
                const int t0 = base + 8 * c;
                if (t0 < inlen)
                    do_chunk<true>(A[c], t0, inlen, skf, aO, aE, r0, Rtot);
            }
        }
        if (last) break;
#pragma unroll
        for (int c = 0; c < 8; ++c) A[c] = Bv[c];
        ++g;
    }
#undef LOADGRP

    // cum_blank = sum_{t<inlen} lp2b(t)
    float s = 0.0f;
#pragma unroll
    for (int j = 0; j < 8; ++j) s += (j * 64 + l < inlen) ? cb8[j] : 0.0f;
    const float cum_b = allsum(s);

    // readout: states 2*LL (aE) and 2*LL-1 (aO) live on lane LL-1
    const float aEr = __shfl(aE, LLv - 1, 64);
    const float aOr = __shfl(aO, LLv - 1, 64);
    if (l == 0)
        out[b] = -LN2_F * (flog2(fmaxf(aEr + aOr, 1e-37f)) + Rtot + cum_b);
}

// ---------------- Fallback: fused single kernel (if ws too small) ----------------
__global__ __launch_bounds__(256, 1) void ctc_fused_kernel(
    const int* __restrict__ y_true, const float* __restrict__ y_pred,
    const int* __restrict__ in_len, const int* __restrict__ lab_len,
    float* __restrict__ lpb_ws, float* __restrict__ out)
{
    __shared__ __half w_lds[Tt * 64];

    const int b   = blockIdx.x;
    const int tid = threadIdx.x;
    const int w   = tid >> 6;
    const int l   = tid & 63;

    int LLv = lab_len[b]; if (LLv < 1) LLv = 1; if (LLv > Ll) LLv = Ll;
    const int lab = y_true[b * Ll + l] & 127;
    const float* rowbase = y_pred + (size_t)b * Tt * Cc;
    float* lpb = lpb_ws + b * Tt;

    const int half = l >> 5, li = l & 31;
    const int srcA = lab >> 2, csel = lab & 3;
    const int tbase = w * 128;
    const bool live = (l < LLv);

    float4 vb[4];
#pragma unroll
    for (int j = 0; j < 4; ++j)
        vb[j] = ((const float4*)(rowbase + (size_t)(tbase + 2 * j + half) * Cc))[li];

    for (int i = 0; i < 64; i += 4) {
#pragma unroll
        for (int j = 0; j < 4; ++j) {
            const float4 v = vb[j];
            const int nx = i + 4 + j;
            if (nx < 64)
                vb[j] = ((const float4*)(rowbase + (size_t)(tbase + 2 * nx + half) * Cc))[li];
            const int rA = tbase + 2 * (i + j), rB = rA + 1;
            float e = (fexp2(v.x * INV_LN2) + fexp2(v.y * INV_LN2))
                    + (fexp2(v.z * INV_LN2) + fexp2(v.w * INV_LN2));
            e = rowsum(e);
            const float sA = rlf(e, 15) + rlf(e, 31);
            const float sB = rlf(e, 47) + rlf(e, 63);
            const float lsA = flog2(sA), lsB = flog2(sB);
            const float blA = rlf(v.w, 31), blB = rlf(v.w, 63);
            if (l == 0)
                ((float2*)(lpb + rA))[0] =
                    make_float2(fmaf(blA, INV_LN2, -lsA), fmaf(blB, INV_LN2, -lsB));
            const float xA = gather4(v, srcA, csel);
            const float xB = gather4(v, srcA + 32, csel);
            float wA = fminf(fmaxf(fexp2((xA - blA) * INV_LN2), 6.1e-5f), 8192.0f);
            float wB = fminf(fmaxf(fexp2((xB - blB) * INV_LN2), 6.1e-5f), 8192.0f);
            w_lds[rA * 64 + l] = __float2half(live ? wA : 0.0f);
            w_lds[rB * 64 + l] = __float2half(live ? wB : 0.0f);
        }
    }

    __syncthreads();
    if (w != 0) return;

    int inlen = in_len[b]; if (inlen < 1) inlen = 1; if (inlen > Tt) inlen = Tt;
    const int labp = __shfl_up(lab, 1, 64);
    const float skf = ((l >= 1) && (lab != labp)) ? 1.0f : 0.0f;

    float cb8[8];
#pragma unroll
    for (int j = 0; j < 8; ++j) cb8[j] = lpb[j * 64 + l];

    float aO = 0.0f, aE = 0.0f, r0 = 1.0f, Rtot = 0.0f;

    const int nfull = inlen >> 3;
    for (int cb = 0; cb < nfull; ++cb) {
        uint4 raw;
        raw.x = *(const unsigned*)&w_lds[(cb * 8 + 0) * 64 + l * 2 / 2];  // not used
        // read 8 halves (lane-strided layout): assemble manually
        unsigned p0 = ((unsigned)__half_as_ushort(w_lds[(cb * 8 + 0) * 64 + l]))
                    | ((unsigned)__half_as_ushort(w_lds[(cb * 8 + 1) * 64 + l]) << 16);
        unsigned p1 = ((unsigned)__half_as_ushort(w_lds[(cb * 8 + 2) * 64 + l]))
                    | ((unsigned)__half_as_ushort(w_lds[(cb * 8 + 3) * 64 + l]) << 16);
        unsigned p2 = ((unsigned)__half_as_ushort(w_lds[(cb * 8 + 4) * 64 + l]))
                    | ((unsigned)__half_as_ushort(w_lds[(cb * 8 + 5) * 64 + l]) << 16);
        unsigned p3 = ((unsigned)__half_as_ushort(w_lds[(cb * 8 + 6) * 64 + l]))
                    | ((unsigned)__half_as_ushort(w_lds[(cb * 8 + 7) * 64 + l]) << 16);
        raw = make_uint4(p0, p1, p2, p3);
        do_chunk<false>(raw, cb * 8, inlen, skf, aO, aE, r0, Rtot);
    }
    const int t0 = nfull << 3;
    if (t0 < inlen) {
        unsigned p[4] = {0, 0, 0, 0};
#pragma unroll
        for (int j = 0; j < 8; ++j) {
            if (t0 + j < Tt) {
                const unsigned hv = __half_as_ushort(w_lds[(t0 + j) * 64 + l]);
                p[j >> 1] |= hv << ((j & 1) * 16);
            }
        }
        do_chunk<true>(make_uint4(p[0], p[1], p[2], p[3]), t0, inlen, skf, aO, aE, r0, Rtot);
    }

    float s = 0.0f;
#pragma unroll
    for (int j = 0; j < 8; ++j) s += (j * 64 + l < inlen) ? cb8[j] : 0.0f;
    const float cum_b = allsum(s);

    const float aEr = __shfl(aE, LLv - 1, 64);
    const float aOr = __shfl(aO, LLv - 1, 64);
    if (l == 0)
        out[b] = -LN2_F * (flog2(fmaxf(aEr + aOr, 1e-37f)) + Rtot + cum_b);
}

extern "C" void kernel_launch(void* const* d_in, const int* in_sizes, int n_in,
                              void* d_out, int out_size, void* d_ws, size_t ws_size,
                              hipStream_t stream) {
    const int*   y_true  = (const int*)d_in[0];    // [256,64]
    const float* y_pred  = (const float*)d_in[1];  // [256,512,128]
    const int*   in_len  = (const int*)d_in[2];    // [256]
    const int*   lab_len = (const int*)d_in[3];    // [256]
    float*       out     = (float*)d_out;          // [256]

    const size_t lpb_bytes = (size_t)256 * Tt * sizeof(float);          // 512 KB
    const size_t w_bytes   = (size_t)256 * NC * 64 * 8 * sizeof(__half); // 16 MB
    float*  lpb = (float*)d_ws;
    __half* wws = (__half*)((char*)d_ws + lpb_bytes);

    if (ws_size >= lpb_bytes + w_bytes) {
        ctc_prep_kernel<<<256, 256, 0, stream>>>(y_true, y_pred, lab_len, lpb, wws);
        ctc_chain_kernel<<<256, 64, 0, stream>>>(y_true, in_len, lab_len, lpb, wws, out);
    } else {
        ctc_fused_kernel<<<256, 256, 0, stream>>>(y_true, y_pred, in_len, lab_len, lpb, out);
    }
}

// Round 8
// 117.354 us; speedup vs baseline: 1.2208x; 1.2208x over previous
//
#include <hip/hip_runtime.h>
#include <hip/hip_fp16.h>
#include <math.h>

// CTC loss forward, SINGLE fused kernel v2. One block of 1024 threads
// (16 waves) per batch element; B=256 blocks = 256 CUs.
// LINEAR-domain recurrence (beta transform), math identical to round 7
// (absmax = 1 bf16 ulp):
//     nO = (aO + pE + skip*pO) * w,  w = e^{x_lab - x_blank}, clamped
//     nE = aE + aO;  state0 = r0;  zero-lag renorm every 8 steps;
//     w = 0 for lanes >= label_length (junk-state flush fix, r6).
// Round-7 lessons: (a) split kernels paid a 32 MB global w round-trip and
// prep ran at 4 waves/CU (latency-bound, 1.2 TB/s); (b) chain-for-b depends
// only on prep-for-b, so fuse with 16 prep waves per block instead:
// prep is HBM-bound (~11-13 us), w stays in LDS (64 KB, chunk layout
// [chunk][lane][8] so the chain does one ds_read_b128 per 8 steps),
// per-wave blank partial sums in LDS kill the chain's lpb reduction.
// B=256, T=512, C=128 (blank=127), L=64, S=129.

constexpr int Cc = 128;
constexpr int Tt = 512;
constexpr int Ll = 64;
constexpr float INV_LN2 = 1.4426950408889634f;
constexpr float LN2_F   = 0.6931471805599453f;

__device__ __forceinline__ float fexp2(float x) { return __builtin_amdgcn_exp2f(x); }
__device__ __forceinline__ float flog2(float x) { return __builtin_amdgcn_logf(x); }

template<int CTRL, bool BC>
__device__ __forceinline__ float dppf(float old, float x) {
    return __int_as_float(__builtin_amdgcn_update_dpp(
        __float_as_int(old), __float_as_int(x), CTRL, 0xF, 0xF, BC));
}
// lane i <- lane i-1 across whole wave; lane 0 <- fill. (silicon-proven r3-r7)
__device__ __forceinline__ float wshr1(float x, float fill) { return dppf<0x138, false>(fill, x); }

__device__ __forceinline__ float rlf(float v, int lane) {
    return __int_as_float(__builtin_amdgcn_readlane(__float_as_int(v), lane));
}
// Row-local (16-lane) reduce; lanes 15/31/47/63 hold row results. (proven r6/r7)
__device__ __forceinline__ float rowsum(float e) {
    e += dppf<0x111, true>(0.f, e);
    e += dppf<0x112, true>(0.f, e);
    e += dppf<0x114, true>(0.f, e);
    e += dppf<0x118, true>(0.f, e);
    return e;
}
__device__ __forceinline__ float rowmax(float m) {   // m >= 0 (0-fill identity)
    m = fmaxf(m, dppf<0x111, true>(0.f, m));
    m = fmaxf(m, dppf<0x112, true>(0.f, m));
    m = fmaxf(m, dppf<0x114, true>(0.f, m));
    m = fmaxf(m, dppf<0x118, true>(0.f, m));
    return m;
}
__device__ __forceinline__ float allmax(float m) {
    m = rowmax(m);
    return fmaxf(fmaxf(rlf(m, 15), rlf(m, 31)), fmaxf(rlf(m, 47), rlf(m, 63)));
}
__device__ __forceinline__ float bperm_f(int srclane, float v) {
    return __int_as_float(__builtin_amdgcn_ds_bpermute(srclane << 2, __float_as_int(v)));
}
__device__ __forceinline__ float gather4(float4 v, int srclane, int csel) {
    const float gx = bperm_f(srclane, v.x), gy = bperm_f(srclane, v.y);
    const float gz = bperm_f(srclane, v.z), gw = bperm_f(srclane, v.w);
    const float lo = (csel & 1) ? gy : gx;
    const float hi = (csel & 1) ? gw : gz;
    return (csel & 2) ? hi : lo;
}

// 8 chain steps + zero-lag renorm on a packed fp16 chunk (proven r7).
template<bool GUARD>
__device__ __forceinline__ void do_chunk(uint4 raw, int t0, int inlen, float skf,
                                         float& aO, float& aE, float& r0, float& Rtot)
{
    float dv[8];
    {
        const __half2 h0 = *reinterpret_cast<const __half2*>(&raw.x);
        const __half2 h1 = *reinterpret_cast<const __half2*>(&raw.y);
        const __half2 h2 = *reinterpret_cast<const __half2*>(&raw.z);
        const __half2 h3 = *reinterpret_cast<const __half2*>(&raw.w);
        dv[0] = __low2float(h0); dv[1] = __high2float(h0);
        dv[2] = __low2float(h1); dv[3] = __high2float(h1);
        dv[4] = __low2float(h2); dv[5] = __high2float(h2);
        dv[6] = __low2float(h3); dv[7] = __high2float(h3);
    }
#pragma unroll
    for (int j = 0; j < 8; ++j) {
        if (!GUARD || (t0 + j < inlen)) {
            const float pE = wshr1(aE, r0);     // beta[2l]; lane0: state0
            const float pO = wshr1(aO, 0.0f);   // beta[2l-1]
            const float nO = (fmaf(skf, pO, pE) + aO) * dv[j];
            aE += aO;
            aO = nO;
        }
    }
    const float M_ = allmax(fmaxf(fmaxf(aO, aE), r0));
    int R_ = (int)(__float_as_uint(M_) >> 23) - 127;
    R_ = (R_ < 0) ? 0 : ((R_ > 126) ? 126 : R_);
    const float sc = __uint_as_float((unsigned)(127 - R_) << 23);
    aO = fminf(aO * sc, 4.0f);
    aE = fminf(aE * sc, 4.0f);
    r0 = fminf(r0 * sc, 4.0f);
    Rtot += (float)R_;
}

__global__ __launch_bounds__(1024, 1) void ctc_fused2_kernel(
    const int* __restrict__ y_true,      // [B, 64]
    const float* __restrict__ y_pred,    // [B, T, C]
    const int* __restrict__ in_len,      // [B]
    const int* __restrict__ lab_len,     // [B]
    float* __restrict__ out)             // [B]
{
    __shared__ __half w_lds[Tt / 8][64][8];   // [chunk][lane][t&7], 64 KB
    __shared__ float  ps[16];                 // per-wave blank partial sums (log2)

    const int b   = blockIdx.x;
    const int tid = threadIdx.x;
    const int w   = tid >> 6;            // wave 0..15
    const int l   = tid & 63;

    int inlen = in_len[b]; if (inlen < 1) inlen = 1; if (inlen > Tt) inlen = Tt;
    int LLv   = lab_len[b]; if (LLv < 1) LLv = 1; if (LLv > Ll) LLv = Ll;

    const int lab = y_true[b * Ll + l] & 127;
    const float* rowbase = y_pred + (size_t)b * Tt * Cc;

    // ---------------- prep: wave w handles rows [w*32, w*32+32) ----------------
    const int half = l >> 5, li = l & 31;
    const int srcA = lab >> 2;           // lane (in low half) holding class `lab`
    const int csel = lab & 3;
    const int tbase = w * 32;
    const bool live = (l < LLv);         // r6 fix: dead lattice lanes -> w = 0

    float4 vb[4];
#pragma unroll
    for (int j = 0; j < 4; ++j)
        vb[j] = ((const float4*)(rowbase + (size_t)(tbase + 2 * j + half) * Cc))[li];

    float acc = 0.0f;                    // sum of lp2_blank over this wave's rows (< inlen)

    for (int i = 0; i < 16; i += 4) {
#pragma unroll
        for (int j = 0; j < 4; ++j) {
            const float4 v = vb[j];
            const int nx = i + 4 + j;
            if (nx < 16)
                vb[j] = ((const float4*)(rowbase + (size_t)(tbase + 2 * nx + half) * Cc))[li];

            const int rA = tbase + 2 * (i + j);
            const int rB = rA + 1;

            // lse (log2) for both rows: row_shr partial sums + readlane combine
            float e = (fexp2(v.x * INV_LN2) + fexp2(v.y * INV_LN2))
                    + (fexp2(v.z * INV_LN2) + fexp2(v.w * INV_LN2));
            e = rowsum(e);
            const float sA = rlf(e, 15) + rlf(e, 31);
            const float sB = rlf(e, 47) + rlf(e, 63);
            const float lsA = flog2(sA), lsB = flog2(sB);
            const float blA = rlf(v.w, 31);      // blank logit, row A (uniform)
            const float blB = rlf(v.w, 63);      // blank logit, row B

            // blank partial sum (uniform across lanes)
            const float lpbA = fmaf(blA, INV_LN2, -lsA);
            const float lpbB = fmaf(blB, INV_LN2, -lsB);
            acc += ((rA < inlen) ? lpbA : 0.0f) + ((rB < inlen) ? lpbB : 0.0f);

            // per-lane label weights -> LDS chunk layout
            const float xA = gather4(v, srcA, csel);
            const float xB = gather4(v, srcA + 32, csel);
            float wA = fminf(fmaxf(fexp2((xA - blA) * INV_LN2), 6.1e-5f), 8192.0f);
            float wB = fminf(fmaxf(fexp2((xB - blB) * INV_LN2), 6.1e-5f), 8192.0f);
            wA = live ? wA : 0.0f;
            wB = live ? wB : 0.0f;
            const unsigned packed =
                  (unsigned)__half_as_ushort(__float2half(wA))
                | ((unsigned)__half_as_ushort(__float2half(wB)) << 16);
            *(unsigned*)&w_lds[rA >> 3][l][rA & 7] = packed;   // rA even: 4B aligned
        }
    }
    if (l == 0) ps[w] = acc;

    __syncthreads();
    if (w != 0) return;

    // ---------------- chain: wave 0, 512-step linear recurrence ----------------
    const int labp = __shfl_up(lab, 1, 64);
    const float skf = ((l >= 1) && (lab != labp)) ? 1.0f : 0.0f;

    float aO = 0.0f, aE = 0.0f, r0 = 1.0f, Rtot = 0.0f;

    const int nchunks = (inlen + 7) >> 3;       // >= 32
    uint4 A = *(const uint4*)&w_lds[0][l][0];
    for (int c = 0; c < nchunks; ++c) {
        const int nx = (c + 1 < Tt / 8) ? c + 1 : Tt / 8 - 1;
        const uint4 Bv = *(const uint4*)&w_lds[nx][l][0];   // prefetch next chunk
        const int t0 = c * 8;
        if (t0 + 8 <= inlen) do_chunk<false>(A, t0, inlen, skf, aO, aE, r0, Rtot);
        else                 do_chunk<true >(A, t0, inlen, skf, aO, aE, r0, Rtot);
        A = Bv;
    }

    // cum_blank (log2): sum the 16 per-wave partials (uniform)
    float cum_b = 0.0f;
#pragma unroll
    for (int q = 0; q < 16; ++q) cum_b += ps[q];

    // readout: states 2*LL (aE) and 2*LL-1 (aO) live on lane LL-1
    const float aEr = __shfl(aE, LLv - 1, 64);
    const float aOr = __shfl(aO, LLv - 1, 64);
    if (l == 0)
        out[b] = -LN2_F * (flog2(fmaxf(aEr + aOr, 1e-37f)) + Rtot + cum_b);
}

extern "C" void kernel_launch(void* const* d_in, const int* in_sizes, int n_in,
                              void* d_out, int out_size, void* d_ws, size_t ws_size,
                              hipStream_t stream) {
    const int*   y_true  = (const int*)d_in[0];    // [256,64]
    const float* y_pred  = (const float*)d_in[1];  // [256,512,128]
    const int*   in_len  = (const int*)d_in[2];    // [256]
    const int*   lab_len = (const int*)d_in[3];    // [256]
    float*       out     = (float*)d_out;          // [256]
    (void)d_ws; (void)ws_size;

    ctc_fused2_kernel<<<256, 1024, 0, stream>>>(y_true, y_pred, in_len, lab_len, out);
}